// Round 11
// baseline (648.934 us; speedup 1.0000x reference)
//
#include <hip/hip_runtime.h>

#define D_  256
#define K_  1024
#define HW_ 1024      // 32*32
#define N_  32768     // 32*HW_

// workspace layout (bytes)
#define WS_COUNTS  262144     // f32[1024]
#define WS_EMBSUM  266240     // f32[262144]
#define WS_LOSS    1314816    // f32
#define WS_NSUM    1314820    // f32
#define WS_ENMAX   1314824    // u32 (max ||e||^2 bits)
#define WS_ZERO0   262144     // zero range start
#define WS_ZEROLEN 1052684    // covers counts..enmax
#define WS_NEWCS   1314828    // f32[1024]
#define WS_ENORM   1318924    // f32[1024]
#define WS_E16     1454096    // fp16(512*E)[1024*256] = 512 KiB (16B aligned)
#define WS_TOTAL   1978384

// output offsets (f32 elements): (z_q_st, loss, indices, new_emb, new_cs, new_es)
#define O_ZQ   0
#define O_LOSS 8388608
#define O_IDX  8388609
#define O_EMB  8421377
#define O_NCS  8683521
#define O_NES  8684545

typedef unsigned short u16;
typedef _Float16 f16x8 __attribute__((ext_vector_type(8)));  // 8 f16 = 4 VGPRs
typedef float f32x4 __attribute__((ext_vector_type(4)));

// pack two f32 -> two f16 (HW v_cvt_f16_f32, rne)
__device__ __forceinline__ unsigned f16x2pack(float a, float b) {
  union { _Float16 h; unsigned short u; } ca, cb;
  ca.h = (_Float16)a; cb.h = (_Float16)b;
  return (unsigned)ca.u | ((unsigned)cb.u << 16);
}

// numpy pairwise_sum of 256 squares: two 128-halves, 8 accumulators,
// combine ((r0+r1)+(r2+r3))+((r4+r5)+(r6+r7)). __f*_rn blocks FMA contraction.
__device__ __forceinline__ float pw256_sq(const float* __restrict__ p, int stride) {
  float tot0 = 0.f, tot1 = 0.f;
#pragma unroll
  for (int h = 0; h < 2; ++h) {
    const float* q = p + h * 128 * stride;
    float r[8];
#pragma unroll
    for (int j = 0; j < 8; ++j) { float x = q[j * stride]; r[j] = __fmul_rn(x, x); }
    for (int i = 8; i < 128; i += 8)
#pragma unroll
      for (int j = 0; j < 8; ++j) {
        float x = q[(i + j) * stride];
        r[j] = __fadd_rn(r[j], __fmul_rn(x, x));
      }
    float s = __fadd_rn(__fadd_rn(__fadd_rn(r[0], r[1]), __fadd_rn(r[2], r[3])),
                        __fadd_rn(__fadd_rn(r[4], r[5]), __fadd_rn(r[6], r[7])));
    if (h == 0) tot0 = s; else tot1 = s;
  }
  return __fadd_rn(tot0, tot1);
}

// ---------------- E prep: ||e||^2 (np order), en_max, E->fp16*512 ----------------
__global__ void vq_eprep(const float* __restrict__ E, float* __restrict__ enorm,
                         u16* __restrict__ E16, unsigned* __restrict__ enmax) {
  int gid = blockIdx.x * 256 + threadIdx.x;   // 32 blocks -> 0..8191
  if (gid < K_) {
    float v = pw256_sq(E + gid * D_, 1);
    enorm[gid] = v;
    atomicMax(enmax, __float_as_uint(v));     // v > 0 -> bit-monotone
  }
  unsigned* E16w = (unsigned*)E16;
  for (int wd = gid; wd < (K_ * D_ / 2); wd += 8192) {
    float2 x = *(const float2*)(E + 2 * wd);
    E16w[wd] = f16x2pack(512.0f * x.x, 512.0f * x.y);
  }
}

// VALU-speed 16-lane min via DPP (quad_perm ^1, ^2, row_half_mirror, row_mirror)
template <int CTRL>
__device__ __forceinline__ float dppmin(float v) {
  int p = __builtin_amdgcn_update_dpp(0, __float_as_int(v), CTRL, 0xF, 0xF, true);
  return fminf(v, __int_as_float(p));
}

// Exact reference-numerics distance (np-order sequential fp32 FMA over d, then
// fl(fl(zn-2a)+en)); z row strided from GLOBAL (L1/L3-hot: staged moments ago),
// E row via float4. Key=(score_bits<<32)|code -> LDS u64 atomicMin (block-final
// best; lowest code wins ties = np argmin). Called only AFTER the MFMA loop
// (round-3 lesson: no calls/liveness across the hot loop). Proven in r10.
__device__ __forceinline__ void exact_update(
    const float* __restrict__ zb, const float* __restrict__ E, int t, int c,
    const float* zn_s, const float* en_s, unsigned long long* best_s) {
  const float* zp = zb + t;             // stride HW_ over d (original f32 z)
  const float* ep = E + c * D_;
  float a = 0.f;
  for (int d0 = 0; d0 < 256; d0 += 8) {
    float zr[8];
#pragma unroll
    for (int j = 0; j < 8; ++j) zr[j] = zp[(d0 + j) * HW_];
    float4 e0 = *(const float4*)(ep + d0);
    float4 e1 = *(const float4*)(ep + d0 + 4);
    a = __fmaf_rn(zr[0], e0.x, a); a = __fmaf_rn(zr[1], e0.y, a);
    a = __fmaf_rn(zr[2], e0.z, a); a = __fmaf_rn(zr[3], e0.w, a);
    a = __fmaf_rn(zr[4], e1.x, a); a = __fmaf_rn(zr[5], e1.y, a);
    a = __fmaf_rn(zr[6], e1.z, a); a = __fmaf_rn(zr[7], e1.w, a);
  }
  float s = __fadd_rn(__fsub_rn(zn_s[t], __fmul_rn(2.0f, a)), en_s[c]);
  unsigned long long key = ((unsigned long long)__float_as_uint(s) << 32) | (unsigned)c;
  atomicMin(&best_s[t], key);
}

#define TCAP 96   // per-wave trigger list (expected ~24 used w/ fp16 margin)

// ---------------- FUSED dist + scatter (r9 structure, r8 tile, r10 consumers) ----------------
// 1024 blocks x 256 thr (256-thread blocks ONLY — r10's 512-thread (512,4)
// spilled 296MB scratch at VGPR=40; (256,4) measured clean 5x at VGPR 56-64).
// Block = 32 tokens x ALL 1024 codes => best block-final => scatter fused.
// Phase A: fp16 MFMA from the r8-proven conflict-free [kb][tok][8d] LDS tile
// (b128 staging writes, 13K conflicts measured vs r9's f32 tile at 6.26M +
// 8192 scalar ds_writes + 16 cvt/step). znorm/exact-verify read z from global
// (L1/L3-hot; np-order bit-identical — proven r10). Margin
// M = 2^-8*sqrt(zn*en_max)+5e-4 (2x the rigorous two-sided fp16 bound) ->
// reference argmin always triggers; exact fp32 chain (np order) decides.
// Phase B: d-major scatter from global z (lane=token: coalesced 128B pairs).
__global__ __launch_bounds__(256, 4) void vq_main(
    const float* __restrict__ z, const float* __restrict__ E,
    const u16* __restrict__ E16, const float* __restrict__ enorm,
    const unsigned* __restrict__ enmax,
    float* __restrict__ embsum, float* __restrict__ loss_sum,
    float* __restrict__ counts, float* __restrict__ out_zq,
    float* __restrict__ out_idx) {
  __shared__ __align__(16) u16 zt[32 * 32 * 8];          // 16 KiB, [kb][tok(32)][8d]
  __shared__ float en_s[K_];                              // 4 KiB
  __shared__ float zn_s[32];
  __shared__ float mg_s[32];
  __shared__ unsigned rmin_s[32];                         // bits of (min ph)+4.0
  __shared__ unsigned long long best_s[32];
  __shared__ unsigned tcount[4];
  __shared__ unsigned tlist[4][TCAP];                     // 1.5 KiB
  __shared__ float wred[4];

  const int tid = threadIdx.x;
  const int tile = blockIdx.x;               // 0..1023
  const int bimg = tile >> 5;
  const int hw0 = (tile & 31) << 5;          // 32 tokens
  const float* zb = z + bimg * (D_ * HW_) + hw0;
  const int n0 = bimg * HW_ + hw0;

  // stage z -> f16 tile (r8-proven). thread: tok = tid&31, kb = (tid>>5)*4 + r.
  {
    const int tok = tid & 31;
    const int kbase = (tid >> 5) * 4;        // 8 groups x 4 kb = 32 kb
    for (int r = 0; r < 4; ++r) {
      int kb = kbase + r;
      unsigned pk[4];
#pragma unroll
      for (int j = 0; j < 4; ++j) {
        float x0 = zb[(kb * 8 + 2 * j) * HW_ + tok];
        float x1 = zb[(kb * 8 + 2 * j + 1) * HW_ + tok];
        pk[j] = f16x2pack(x0, x1);
      }
      uint4 wv; wv.x = pk[0]; wv.y = pk[1]; wv.z = pk[2]; wv.w = pk[3];
      *(uint4*)(zt + kb * 256 + tok * 8) = wv;       // 16B, conflict-free
    }
  }
  if (tid < 32) {
    float zn = pw256_sq(zb + tid, HW_);      // np order, global strided (L1-hot)
    zn_s[tid] = zn;
    float em = __uint_as_float(*enmax);
    mg_s[tid] = 0.00390625f * sqrtf(zn * em) + 5e-4f;  // fp16 margin (proven safe)
    rmin_s[tid] = 0xFFFFFFFFu;
    best_s[tid] = ~0ull;
  }
  if (tid < 4) tcount[tid] = 0;
  for (int i = tid; i < K_; i += 256) en_s[i] = enorm[i];
  __syncthreads();

  const int lane = tid & 63;
  const int w = tid >> 6;                    // 0..3
  const int l15 = lane & 15, g = lane >> 4;
  const int cw = w * 256;                    // wave's code base (256 codes)
  const u16* Eb = E16 + (unsigned)(cw + l15) * D_ + g * 8;

  f16x8 efA[2], efB[2];
#pragma unroll
  for (int n = 0; n < 2; ++n)
    efA[n] = *(const f16x8*)(Eb + n * 16 * D_);          // prime: s=0 (ch0,kk0)

  f32x4 acc[2][2];

// one MFMA step (r8-proven): ef ping-pong; zf from conflict-free fp16 tile.
// No branches, no calls in the loop (rounds 2/3 lessons).
#define MSTEP(S, EFU, EFF, SN)                                                   \
  {                                                                              \
    const int kk_ = (S) & 7;                                                     \
    {                                                                            \
      const int cn_ = (SN) >> 3, kn_ = (SN) & 7;                                 \
      _Pragma("unroll")                                                          \
      for (int n = 0; n < 2; ++n)                                                \
        EFF[n] = *(const f16x8*)(Eb + (cn_ * 32 + n * 16) * D_ + kn_ * 32);      \
    }                                                                            \
    f16x8 zf_[2];                                                                \
    _Pragma("unroll")                                                            \
    for (int m = 0; m < 2; ++m)                                                  \
      zf_[m] = *(const f16x8*)(zt + (kk_ * 4 + g) * 256 + (m * 16 + l15) * 8);   \
    _Pragma("unroll")                                                            \
    for (int m = 0; m < 2; ++m)                                                  \
      _Pragma("unroll")                                                          \
      for (int n = 0; n < 2; ++n)                                                \
        acc[m][n] = __builtin_amdgcn_mfma_f32_16x16x32_f16(zf_[m], EFU[n],       \
                                                           acc[m][n], 0, 0, 0);  \
  }

  for (int s2 = 0; s2 < 64; s2 += 2) {      // 8 chunks x 8 kk
    if ((s2 & 7) == 0) {
      f32x4 z4 = {0.f, 0.f, 0.f, 0.f};
#pragma unroll
      for (int m = 0; m < 2; ++m)
#pragma unroll
        for (int n = 0; n < 2; ++n) acc[m][n] = z4;
    }
    MSTEP(s2, efA, efB, s2 + 1)
    MSTEP(s2 + 1, efB, efA, (s2 + 2) & 63)   // tail wrap value never consumed
    if ((s2 & 7) == 6) {                     // chunk end
      const int cb = cw + (s2 >> 3) * 32;
      // ph = en - 2*(A/512) = fma(-1/256, A, en); D: col=l15(code), row=g*4+r(tok)
      float enc[2];
#pragma unroll
      for (int n = 0; n < 2; ++n) enc[n] = en_s[cb + n * 16 + l15];
#pragma unroll
      for (int m = 0; m < 2; ++m)
#pragma unroll
        for (int n = 0; n < 2; ++n)
#pragma unroll
          for (int r = 0; r < 4; ++r)
            acc[m][n][r] = __builtin_fmaf(-0.00390625f, acc[m][n][r], enc[n]);
#pragma unroll
      for (int m = 0; m < 2; ++m)
#pragma unroll
        for (int r = 0; r < 4; ++r) {
          float v = fminf(acc[m][0][r], acc[m][1][r]);
          v = dppmin<0xB1>(v);     // ^1
          v = dppmin<0x4E>(v);     // ^2
          v = dppmin<0x141>(v);    // row_half_mirror
          v = dppmin<0x140>(v);    // row_mirror
          if (l15 == 0) atomicMin(&rmin_s[m * 16 + g * 4 + r], __float_as_uint(v + 4.0f));
        }
#pragma unroll
      for (int m = 0; m < 2; ++m)
#pragma unroll
        for (int r = 0; r < 4; ++r) {
          int t = m * 16 + g * 4 + r;
          float thr = (__uint_as_float(rmin_s[t]) - 4.0f) + mg_s[t];
#pragma unroll
          for (int n = 0; n < 2; ++n) {
            if (acc[m][n][r] <= thr) {
              unsigned pos = atomicAdd(&tcount[w], 1u);
              if (pos < TCAP)
                tlist[w][pos] = ((unsigned)t << 16) | (unsigned)(cb + n * 16 + l15);
            }
          }
        }
    }
  }
#undef MSTEP

  // drain own wave's triggers: exact recompute (global z + global E) -> best_s
  {
    unsigned cnt = tcount[w];
    if (cnt <= TCAP) {
      for (unsigned basei = 0; basei < cnt; basei += 64) {
        unsigned i = basei + (unsigned)lane;
        if (i < cnt) {
          unsigned e = tlist[w][i];
          exact_update(zb, E, (int)(e >> 16), (int)(e & 1023u), zn_s, en_s, best_s);
        }
      }
    } else {
      // overflow (astronomically rare): exact-verify wave's whole 32x256 tile
      for (unsigned i = (unsigned)lane; i < 32u * 256u; i += 64) {
        exact_update(zb, E, (int)(i >> 8), cw + (int)(i & 255u), zn_s, en_s, best_s);
      }
    }
  }
  __syncthreads();   // best_s final across all waves

  // ---------------- phase B: d-major scatter from global z ----------------
  if (tid < 32) {
    int k = (int)(best_s[tid] & 1023ull);
    out_idx[n0 + tid] = (float)k;
    atomicAdd(&counts[k], 1.0f);
  }
  // lane: h = lane>>5 (half), t = lane&31 (token); wave w + half h own
  // d in [(w*2+h)*32, +32). Unique (t,d) owner; z/zq accesses are 2x128B
  // coalesced segments per instruction; E/embsum per-lane scalar (L2).
  {
    const int h = lane >> 5, t = lane & 31;
    const int myk = (int)(best_s[t] & 1023ull);
    const float* Er = E + myk * D_;
    float* es = embsum + myk * D_;
    float* ob = out_zq + bimg * (D_ * HW_) + hw0;
    const int d0 = (w * 2 + h) * 32;
    float lsum = 0.f;
    for (int dd = 0; dd < 32; ++dd) {
      int d = d0 + dd;
      float zv = zb[d * HW_ + t];
      float e = Er[d];
      float df = __fsub_rn(zv, e);
      lsum += df * df;
      ob[d * HW_ + t] = __fadd_rn(zv, __fsub_rn(e, zv));  // ref: z + (z_q - z)
      atomicAdd(es + d, zv);
    }
#pragma unroll
    for (int o = 32; o > 0; o >>= 1) lsum += __shfl_down(lsum, o, 64);
    if (lane == 0) wred[w] = lsum;
  }
  __syncthreads();
  if (tid == 0)
    atomicAdd(loss_sum, (wred[0] + wred[1]) + (wred[2] + wred[3]));
}

// ---------------- EMA cluster-size + n + loss finalize ----------------
__global__ void vq_newcs_v7(const float* __restrict__ cs_in, const float* __restrict__ counts,
                            float* __restrict__ newcs, float* __restrict__ nsum,
                            const float* __restrict__ loss_sum,
                            float* __restrict__ out_loss, float* __restrict__ out_ncs) {
  int k = blockIdx.x * 256 + threadIdx.x;
  float v = __fadd_rn(__fmul_rn(0.99f, cs_in[k]), __fmul_rn(0.01f, counts[k]));
  newcs[k] = v;
  out_ncs[k] = v;
  float s = v;
#pragma unroll
  for (int o = 32; o > 0; o >>= 1) s += __shfl_down(s, o, 64);
  __shared__ float w[4];
  if ((threadIdx.x & 63) == 0) w[threadIdx.x >> 6] = s;
  __syncthreads();
  if (threadIdx.x == 0) atomicAdd(nsum, w[0] + w[1] + w[2] + w[3]);
  if (k == 0) out_loss[0] = loss_sum[0] * (1.0f / 8388608.0f);
}

// ---------------- new_es + new_embedding ----------------
__global__ void vq_newemb_v7(const float* __restrict__ es_in, const float* __restrict__ embsum,
                             const float* __restrict__ newcs, const float* __restrict__ nsum,
                             float* __restrict__ out_emb, float* __restrict__ out_nes) {
  int k = blockIdx.x, d = threadIdx.x;
  float n = *nsum;
  float cs = (newcs[k] + 1e-5f) / (n + 1024.0f * 1e-5f) * n;   // ref formula order
  float es = __fadd_rn(__fmul_rn(0.99f, es_in[k * D_ + d]),
                       __fmul_rn(0.01f, embsum[k * D_ + d]));
  out_nes[k * D_ + d] = es;
  out_emb[k * D_ + d] = es / cs;
}

extern "C" void kernel_launch(void* const* d_in, const int* in_sizes, int n_in,
                              void* d_out, int out_size, void* d_ws, size_t ws_size,
                              hipStream_t stream) {
  (void)in_sizes; (void)n_in; (void)out_size; (void)ws_size;
  const float* z       = (const float*)d_in[0];
  const float* E       = (const float*)d_in[1];
  const float* ema_cs  = (const float*)d_in[2];
  const float* ema_es  = (const float*)d_in[3];
  float* out = (float*)d_out;
  char* ws = (char*)d_ws;
  float* counts = (float*)(ws + WS_COUNTS);
  float* embsum = (float*)(ws + WS_EMBSUM);
  float* loss_s = (float*)(ws + WS_LOSS);
  float* nsum   = (float*)(ws + WS_NSUM);
  unsigned* enmax = (unsigned*)(ws + WS_ENMAX);
  float* newcs  = (float*)(ws + WS_NEWCS);
  float* enorm  = (float*)(ws + WS_ENORM);
  u16*   e16    = (u16*)(ws + WS_E16);

  hipMemsetAsync(ws + WS_ZERO0, 0, WS_ZEROLEN, stream);   // counts/embsum/loss/nsum/enmax
  vq_eprep<<<dim3(32), dim3(256), 0, stream>>>(E, enorm, e16, enmax);
  vq_main<<<dim3(1024), dim3(256), 0, stream>>>(z, E, e16, enorm, enmax,
                                                embsum, loss_s, counts,
                                                out + O_ZQ, out + O_IDX);
  vq_newcs_v7<<<dim3(4), dim3(256), 0, stream>>>(ema_cs, counts, newcs, nsum, loss_s,
                                                 out + O_LOSS, out + O_NCS);
  vq_newemb_v7<<<dim3(K_), dim3(256), 0, stream>>>(ema_es, embsum, newcs, nsum,
                                                   out + O_EMB, out + O_NES);
}

// Round 12
// 215.244 us; speedup vs baseline: 3.0149x; 3.0149x over previous
//
#include <hip/hip_runtime.h>

#define D_  256
#define K_  1024
#define HW_ 1024      // 32*32
#define N_  32768     // 32*HW_

// workspace layout (bytes)
#define WS_COUNTS  262144     // f32[1024]
#define WS_EMBSUM  266240     // f32[262144]
#define WS_LOSS    1314816    // f32
#define WS_NSUM    1314820    // f32
#define WS_ENMAX   1314824    // u32 (max ||e||^2 bits)
#define WS_ZERO0   262144     // zero range start
#define WS_ZEROLEN 1052684    // covers counts..enmax
#define WS_NEWCS   1314828    // f32[1024]
#define WS_ENORM   1318924    // f32[1024]
#define WS_E16     1454096    // fp16(512*E)[1024*256] = 512 KiB (16B aligned)
#define WS_TOTAL   1978384

// output offsets (f32 elements): (z_q_st, loss, indices, new_emb, new_cs, new_es)
#define O_ZQ   0
#define O_LOSS 8388608
#define O_IDX  8388609
#define O_EMB  8421377
#define O_NCS  8683521
#define O_NES  8684545

typedef unsigned short u16;
typedef _Float16 f16x8 __attribute__((ext_vector_type(8)));  // 8 f16 = 4 VGPRs
typedef float f32x4 __attribute__((ext_vector_type(4)));

// pack two f32 -> two f16 (HW v_cvt_f16_f32, rne)
__device__ __forceinline__ unsigned f16x2pack(float a, float b) {
  union { _Float16 h; unsigned short u; } ca, cb;
  ca.h = (_Float16)a; cb.h = (_Float16)b;
  return (unsigned)ca.u | ((unsigned)cb.u << 16);
}

// numpy pairwise_sum of 256 squares: two 128-halves, 8 accumulators,
// combine ((r0+r1)+(r2+r3))+((r4+r5)+(r6+r7)). __f*_rn blocks FMA contraction.
__device__ __forceinline__ float pw256_sq(const float* __restrict__ p, int stride) {
  float tot0 = 0.f, tot1 = 0.f;
#pragma unroll
  for (int h = 0; h < 2; ++h) {
    const float* q = p + h * 128 * stride;
    float r[8];
#pragma unroll
    for (int j = 0; j < 8; ++j) { float x = q[j * stride]; r[j] = __fmul_rn(x, x); }
    for (int i = 8; i < 128; i += 8)
#pragma unroll
      for (int j = 0; j < 8; ++j) {
        float x = q[(i + j) * stride];
        r[j] = __fadd_rn(r[j], __fmul_rn(x, x));
      }
    float s = __fadd_rn(__fadd_rn(__fadd_rn(r[0], r[1]), __fadd_rn(r[2], r[3])),
                        __fadd_rn(__fadd_rn(r[4], r[5]), __fadd_rn(r[6], r[7])));
    if (h == 0) tot0 = s; else tot1 = s;
  }
  return __fadd_rn(tot0, tot1);
}

// ---------------- E prep: ||e||^2 (np order), en_max, E->fp16*512 ----------------
// ROUND-12: widened 4 -> 32 blocks (r9 ran this on 4 CUs, serializing ~40-60us
// before vq_main, which consumes enorm/enmax/E16). Same math, same np order.
__global__ void vq_eprep(const float* __restrict__ E, float* __restrict__ enorm,
                         u16* __restrict__ E16, unsigned* __restrict__ enmax) {
  int gid = blockIdx.x * 256 + threadIdx.x;   // 32 blocks -> 0..8191
  if (gid < K_) {
    float v = pw256_sq(E + gid * D_, 1);
    enorm[gid] = v;
    atomicMax(enmax, __float_as_uint(v));     // v > 0 -> bit-monotone
  }
  unsigned* E16w = (unsigned*)E16;
  for (int wd = gid; wd < (K_ * D_ / 2); wd += 8192) {
    float2 x = *(const float2*)(E + 2 * wd);
    E16w[wd] = f16x2pack(512.0f * x.x, 512.0f * x.y);
  }
}

// VALU-speed 16-lane min via DPP (quad_perm ^1, ^2, row_half_mirror, row_mirror)
template <int CTRL>
__device__ __forceinline__ float dppmin(float v) {
  int p = __builtin_amdgcn_update_dpp(0, __float_as_int(v), CTRL, 0xF, 0xF, true);
  return fminf(v, __int_as_float(p));
}

// Exact reference-numerics distance (np-order sequential fp32 FMA over d, then
// fl(fl(zn-2a)+en)); z row from LDS (contiguous f32), E row from global.
// Key=(score_bits<<32)|code -> LDS u64 atomicMin (block-final best; lowest
// code wins ties = np argmin). forceinline: only 2 call sites, both AFTER the
// MFMA loop (round-3 lesson: no calls with live acc/ef).
__device__ __forceinline__ void exact_update(
    const float* zrow, const float* __restrict__ E, int t, int c,
    const float* zn_s, const float* en_s, unsigned long long* best_s) {
  const float* ep = E + c * D_;
  float a = 0.f;
  for (int d0 = 0; d0 < 256; d0 += 8) {
    f32x4 z0 = *(const f32x4*)(zrow + d0);
    f32x4 z1 = *(const f32x4*)(zrow + d0 + 4);
    float4 e0 = *(const float4*)(ep + d0);
    float4 e1 = *(const float4*)(ep + d0 + 4);
    a = __fmaf_rn(z0[0], e0.x, a); a = __fmaf_rn(z0[1], e0.y, a);
    a = __fmaf_rn(z0[2], e0.z, a); a = __fmaf_rn(z0[3], e0.w, a);
    a = __fmaf_rn(z1[0], e1.x, a); a = __fmaf_rn(z1[1], e1.y, a);
    a = __fmaf_rn(z1[2], e1.z, a); a = __fmaf_rn(z1[3], e1.w, a);
  }
  float s = __fadd_rn(__fsub_rn(zn_s[t], __fmul_rn(2.0f, a)), en_s[c]);
  unsigned long long key = ((unsigned long long)__float_as_uint(s) << 32) | (unsigned)c;
  atomicMin(&best_s[t], key);
}

#define TCAP 96   // per-wave trigger list (expected ~24 used w/ fp16 margin)
#define ZP  260   // zs row pad: 260*4B = 1040 ≡ 0 mod 16 (b128-aligned rows)

// ---------------- FUSED dist + scatter (round-9 kernel, byte-identical) ----------------
// 1024 blocks x 256 thr, ~39.6 KB LDS -> 4 blocks/CU. Block = 32 tokens x ALL
// 1024 codes => best is block-final (no cross-block merge) => scatter fuses in.
// Measured clean (r9): 128us, VGPR=64, no spill. Rounds 10/11 rewrites of this
// body both collapsed to VGPR=40 + ~170-220MB scratch -> DO NOT restructure;
// A/B single changes only from this baseline.
// Phase A: MFMA fp16 approx scores (z cvt'd f32->f16 on the fly from the LDS
// f32 tile), per-token running min, margin-gated trigger list, exact fp32
// re-verify into LDS best_s. Margin M = 2^-8*sqrt(zn*en_max)+5e-4 (2x the
// rigorous two-sided fp16 bound) -> reference argmin always triggers.
// Phase B: scatter body on the same LDS tile (loss, z_q_st in-place,
// embsum atomics, counts, idx).
__global__ __launch_bounds__(256, 4) void vq_main(
    const float* __restrict__ z, const float* __restrict__ E,
    const u16* __restrict__ E16, const float* __restrict__ enorm,
    const unsigned* __restrict__ enmax,
    float* __restrict__ embsum, float* __restrict__ loss_sum,
    float* __restrict__ counts, float* __restrict__ out_zq,
    float* __restrict__ out_idx) {
  __shared__ __align__(16) float zs[32 * ZP];            // 33280 B, [tok][d]
  __shared__ float en_s[K_];                              // 4 KiB
  __shared__ float zn_s[32];
  __shared__ float mg_s[32];
  __shared__ unsigned rmin_s[32];                         // bits of (min ph)+4.0
  __shared__ unsigned long long best_s[32];
  __shared__ unsigned tcount[4];
  __shared__ unsigned tlist[4][TCAP];                     // 1.5 KiB
  __shared__ float wred[4];

  const int tid = threadIdx.x;
  const int tile = blockIdx.x;               // 0..1023
  const int bimg = tile >> 5;
  const int hw0 = (tile & 31) << 5;          // 32 tokens
  const float* zb = z + bimg * (D_ * HW_) + hw0;
  const int n0 = bimg * HW_ + hw0;

  // stage z f32 -> zs[t][d] (coalesced float4 global reads, scalar LDS writes)
#pragma unroll
  for (int r = 0; r < 8; ++r) {
    int ii = r * 256 + tid;
    int d = ii >> 3, t4 = (ii & 7) * 4;
    float4 v = *(const float4*)(zb + d * HW_ + t4);
    zs[(t4 + 0) * ZP + d] = v.x; zs[(t4 + 1) * ZP + d] = v.y;
    zs[(t4 + 2) * ZP + d] = v.z; zs[(t4 + 3) * ZP + d] = v.w;
  }
  for (int i = tid; i < K_; i += 256) en_s[i] = enorm[i];
  if (tid < 4) tcount[tid] = 0;
  __syncthreads();
  if (tid < 32) {
    float zn = pw256_sq(&zs[tid * ZP], 1);   // np order, bit-identical values
    zn_s[tid] = zn;
    float em = __uint_as_float(*enmax);
    mg_s[tid] = 0.00390625f * sqrtf(zn * em) + 5e-4f;  // fp16 margin (proven safe)
    rmin_s[tid] = 0xFFFFFFFFu;
    best_s[tid] = ~0ull;
  }
  __syncthreads();

  const int lane = tid & 63;
  const int w = tid >> 6;
  const int l15 = lane & 15, g = lane >> 4;
  const int cw = w * 256;                    // wave's code base
  const u16* Eb = E16 + (unsigned)(cw + l15) * D_ + g * 8;

  f16x8 efA[2], efB[2];
#pragma unroll
  for (int n = 0; n < 2; ++n)
    efA[n] = *(const f16x8*)(Eb + n * 16 * D_);          // prime: s=0 (ch0,kk0)

  f32x4 acc[2][2];

// one MFMA step: ef ping-pong (dist-1; best-measured), z fragment read as f32
// from zs + cvt to fp16 (same rne values as the old pre-converted tile).
// No branches, no calls in the loop.
#define MSTEP(S, EFU, EFF, SN)                                                   \
  {                                                                              \
    const int kk_ = (S) & 7;                                                     \
    {                                                                            \
      const int cn_ = (SN) >> 3, kn_ = (SN) & 7;                                 \
      _Pragma("unroll")                                                          \
      for (int n = 0; n < 2; ++n)                                                \
        EFF[n] = *(const f16x8*)(Eb + (cn_ * 32 + n * 16) * D_ + kn_ * 32);      \
    }                                                                            \
    f16x8 zf_[2];                                                                \
    _Pragma("unroll")                                                            \
    for (int m = 0; m < 2; ++m) {                                                \
      const float* zr = zs + (m * 16 + l15) * ZP + kk_ * 32 + g * 8;             \
      f32x4 lo = *(const f32x4*)zr;                                              \
      f32x4 hi = *(const f32x4*)(zr + 4);                                        \
      f16x8 zc;                                                                  \
      _Pragma("unroll")                                                          \
      for (int j = 0; j < 4; ++j) {                                              \
        zc[j] = (_Float16)lo[j]; zc[4 + j] = (_Float16)hi[j];                    \
      }                                                                          \
      zf_[m] = zc;                                                               \
    }                                                                            \
    _Pragma("unroll")                                                            \
    for (int m = 0; m < 2; ++m)                                                  \
      _Pragma("unroll")                                                          \
      for (int n = 0; n < 2; ++n)                                                \
        acc[m][n] = __builtin_amdgcn_mfma_f32_16x16x32_f16(zf_[m], EFU[n],       \
                                                           acc[m][n], 0, 0, 0);  \
  }

  for (int s2 = 0; s2 < 64; s2 += 2) {      // 8 chunks x 8 kk
    if ((s2 & 7) == 0) {
      f32x4 z4 = {0.f, 0.f, 0.f, 0.f};
#pragma unroll
      for (int m = 0; m < 2; ++m)
#pragma unroll
        for (int n = 0; n < 2; ++n) acc[m][n] = z4;
    }
    MSTEP(s2, efA, efB, s2 + 1)
    MSTEP(s2 + 1, efB, efA, (s2 + 2) & 63)   // tail wrap value never consumed
    if ((s2 & 7) == 6) {                     // chunk end
      const int cb = cw + (s2 >> 3) * 32;
      // ph = en - 2*(A/512) = fma(-1/256, A, en); D: col=l15(code), row=g*4+r(tok)
      float enc[2];
#pragma unroll
      for (int n = 0; n < 2; ++n) enc[n] = en_s[cb + n * 16 + l15];
#pragma unroll
      for (int m = 0; m < 2; ++m)
#pragma unroll
        for (int n = 0; n < 2; ++n)
#pragma unroll
          for (int r = 0; r < 4; ++r)
            acc[m][n][r] = __builtin_fmaf(-0.00390625f, acc[m][n][r], enc[n]);
#pragma unroll
      for (int m = 0; m < 2; ++m)
#pragma unroll
        for (int r = 0; r < 4; ++r) {
          float v = fminf(acc[m][0][r], acc[m][1][r]);
          v = dppmin<0xB1>(v);     // ^1
          v = dppmin<0x4E>(v);     // ^2
          v = dppmin<0x141>(v);    // row_half_mirror
          v = dppmin<0x140>(v);    // row_mirror
          if (l15 == 0) atomicMin(&rmin_s[m * 16 + g * 4 + r], __float_as_uint(v + 4.0f));
        }
#pragma unroll
      for (int m = 0; m < 2; ++m)
#pragma unroll
        for (int r = 0; r < 4; ++r) {
          int t = m * 16 + g * 4 + r;
          float thr = (__uint_as_float(rmin_s[t]) - 4.0f) + mg_s[t];
#pragma unroll
          for (int n = 0; n < 2; ++n) {
            if (acc[m][n][r] <= thr) {
              unsigned pos = atomicAdd(&tcount[w], 1u);
              if (pos < TCAP)
                tlist[w][pos] = ((unsigned)t << 16) | (unsigned)(cb + n * 16 + l15);
            }
          }
        }
    }
  }
#undef MSTEP

  // drain own wave's triggers: exact recompute (LDS z row + global E) -> best_s
  {
    unsigned cnt = tcount[w];
    if (cnt <= TCAP) {
      for (unsigned basei = 0; basei < cnt; basei += 64) {
        unsigned i = basei + (unsigned)lane;
        if (i < cnt) {
          unsigned e = tlist[w][i];
          int t = (int)(e >> 16), c = (int)(e & 1023u);
          exact_update(&zs[t * ZP], E, t, c, zn_s, en_s, best_s);
        }
      }
    } else {
      // overflow (astronomically rare): exact-verify wave's whole 32x256 tile
      for (unsigned i = (unsigned)lane; i < 32u * 256u; i += 64) {
        int t = (int)(i >> 8), c = cw + (int)(i & 255u);
        exact_update(&zs[t * ZP], E, t, c, zn_s, en_s, best_s);
      }
    }
  }
  __syncthreads();   // best_s final; zs reads done -> phase B may overwrite

  // ---------------- phase B: scatter body on the same LDS tile ----------------
  if (tid < 32) {
    int k = (int)(best_s[tid] & 1023ull);
    out_idx[n0 + tid] = (float)k;
    atomicAdd(&counts[k], 1.0f);
  }
  float lsum = 0.f;
  for (int tt = 0; tt < 8; ++tt) {
    int t = w * 8 + tt;
    int k = (int)(best_s[t] & 1023ull);    // wave-uniform
    const float* Er = E + k * D_;
    float* es = embsum + k * D_;
#pragma unroll
    for (int i = 0; i < 4; ++i) {
      int d = i * 64 + lane;
      float e = Er[d];
      float zv = zs[t * ZP + d];           // unique (t,d) owner -> safe in-place
      float df = __fsub_rn(zv, e);
      lsum += df * df;
      zs[t * ZP + d] = __fadd_rn(zv, __fsub_rn(e, zv));  // ref: z + (z_q - z)
      atomicAdd(es + d, zv);
    }
  }
#pragma unroll
  for (int o = 32; o > 0; o >>= 1) lsum += __shfl_down(lsum, o, 64);
  if (lane == 0) wred[w] = lsum;
  __syncthreads();
  if (tid == 0) atomicAdd(loss_sum, wred[0] + wred[1] + wred[2] + wred[3]);

  float* ob = out_zq + bimg * (D_ * HW_) + hw0;
#pragma unroll 4
  for (int r = 0; r < 32; ++r) {
    int d = r * 8 + (tid >> 5);
    int t = tid & 31;
    ob[d * HW_ + t] = zs[t * ZP + d];      // coalesced 128B-chunk f32 stores
  }
}

// ---------------- EMA cluster-size + n + loss finalize ----------------
__global__ void vq_newcs_v7(const float* __restrict__ cs_in, const float* __restrict__ counts,
                            float* __restrict__ newcs, float* __restrict__ nsum,
                            const float* __restrict__ loss_sum,
                            float* __restrict__ out_loss, float* __restrict__ out_ncs) {
  int k = blockIdx.x * 256 + threadIdx.x;
  float v = __fadd_rn(__fmul_rn(0.99f, cs_in[k]), __fmul_rn(0.01f, counts[k]));
  newcs[k] = v;
  out_ncs[k] = v;
  float s = v;
#pragma unroll
  for (int o = 32; o > 0; o >>= 1) s += __shfl_down(s, o, 64);
  __shared__ float w[4];
  if ((threadIdx.x & 63) == 0) w[threadIdx.x >> 6] = s;
  __syncthreads();
  if (threadIdx.x == 0) atomicAdd(nsum, w[0] + w[1] + w[2] + w[3]);
  if (k == 0) out_loss[0] = loss_sum[0] * (1.0f / 8388608.0f);
}

// ---------------- new_es + new_embedding ----------------
__global__ void vq_newemb_v7(const float* __restrict__ es_in, const float* __restrict__ embsum,
                             const float* __restrict__ newcs, const float* __restrict__ nsum,
                             float* __restrict__ out_emb, float* __restrict__ out_nes) {
  int k = blockIdx.x, d = threadIdx.x;
  float n = *nsum;
  float cs = (newcs[k] + 1e-5f) / (n + 1024.0f * 1e-5f) * n;   // ref formula order
  float es = __fadd_rn(__fmul_rn(0.99f, es_in[k * D_ + d]),
                       __fmul_rn(0.01f, embsum[k * D_ + d]));
  out_nes[k * D_ + d] = es;
  out_emb[k * D_ + d] = es / cs;
}

extern "C" void kernel_launch(void* const* d_in, const int* in_sizes, int n_in,
                              void* d_out, int out_size, void* d_ws, size_t ws_size,
                              hipStream_t stream) {
  (void)in_sizes; (void)n_in; (void)out_size; (void)ws_size;
  const float* z       = (const float*)d_in[0];
  const float* E       = (const float*)d_in[1];
  const float* ema_cs  = (const float*)d_in[2];
  const float* ema_es  = (const float*)d_in[3];
  float* out = (float*)d_out;
  char* ws = (char*)d_ws;
  float* counts = (float*)(ws + WS_COUNTS);
  float* embsum = (float*)(ws + WS_EMBSUM);
  float* loss_s = (float*)(ws + WS_LOSS);
  float* nsum   = (float*)(ws + WS_NSUM);
  unsigned* enmax = (unsigned*)(ws + WS_ENMAX);
  float* newcs  = (float*)(ws + WS_NEWCS);
  float* enorm  = (float*)(ws + WS_ENORM);
  u16*   e16    = (u16*)(ws + WS_E16);

  hipMemsetAsync(ws + WS_ZERO0, 0, WS_ZEROLEN, stream);   // counts/embsum/loss/nsum/enmax
  vq_eprep<<<dim3(32), dim3(256), 0, stream>>>(E, enorm, e16, enmax);
  vq_main<<<dim3(1024), dim3(256), 0, stream>>>(z, E, e16, enorm, enmax,
                                                embsum, loss_s, counts,
                                                out + O_ZQ, out + O_IDX);
  vq_newcs_v7<<<dim3(4), dim3(256), 0, stream>>>(ema_cs, counts, newcs, nsum, loss_s,
                                                 out + O_LOSS, out + O_NCS);
  vq_newemb_v7<<<dim3(K_), dim3(256), 0, stream>>>(ema_es, embsum, newcs, nsum,
                                                   out + O_EMB, out + O_NES);
}

// Round 13
// 209.495 us; speedup vs baseline: 3.0976x; 1.0274x over previous
//
#include <hip/hip_runtime.h>

#define D_  256
#define K_  1024
#define HW_ 1024      // 32*32
#define N_  32768     // 32*HW_

// workspace layout (bytes)
#define WS_COUNTS  262144     // f32[1024]   (zeroed by vq_eprep)
#define WS_EMBSUM  266240     // f32[262144] (zeroed by vq_eprep)
#define WS_LOSS    1314816    // f32         (zeroed by vq_eprep)
#define WS_NSUM    1314820    // f32         (unused now; kept for layout)
#define WS_ENORM   1318924    // f32[1024]
#define WS_E16     1454096    // fp16(512*E)[1024*256] = 512 KiB (16B aligned)
#define WS_TOTAL   1978384

// output offsets (f32 elements): (z_q_st, loss, indices, new_emb, new_cs, new_es)
#define O_ZQ   0
#define O_LOSS 8388608
#define O_IDX  8388609
#define O_EMB  8421377
#define O_NCS  8683521
#define O_NES  8684545

typedef unsigned short u16;
typedef _Float16 f16x8 __attribute__((ext_vector_type(8)));  // 8 f16 = 4 VGPRs
typedef float f32x4 __attribute__((ext_vector_type(4)));

// pack two f32 -> two f16 (HW v_cvt_f16_f32, rne)
__device__ __forceinline__ unsigned f16x2pack(float a, float b) {
  union { _Float16 h; unsigned short u; } ca, cb;
  ca.h = (_Float16)a; cb.h = (_Float16)b;
  return (unsigned)ca.u | ((unsigned)cb.u << 16);
}

// numpy pairwise_sum of 256 squares: two 128-halves, 8 accumulators,
// combine ((r0+r1)+(r2+r3))+((r4+r5)+(r6+r7)). __f*_rn blocks FMA contraction.
__device__ __forceinline__ float pw256_sq(const float* __restrict__ p, int stride) {
  float tot0 = 0.f, tot1 = 0.f;
#pragma unroll
  for (int h = 0; h < 2; ++h) {
    const float* q = p + h * 128 * stride;
    float r[8];
#pragma unroll
    for (int j = 0; j < 8; ++j) { float x = q[j * stride]; r[j] = __fmul_rn(x, x); }
    for (int i = 8; i < 128; i += 8)
#pragma unroll
      for (int j = 0; j < 8; ++j) {
        float x = q[(i + j) * stride];
        r[j] = __fadd_rn(r[j], __fmul_rn(x, x));
      }
    float s = __fadd_rn(__fadd_rn(__fadd_rn(r[0], r[1]), __fadd_rn(r[2], r[3])),
                        __fadd_rn(__fadd_rn(r[4], r[5]), __fadd_rn(r[6], r[7])));
    if (h == 0) tot0 = s; else tot1 = s;
  }
  return __fadd_rn(tot0, tot1);
}

// ---------------- E prep: ||e||^2 (np order), E->fp16*512, workspace zeroing ----------------
// ROUND-13: absorbs the hipMemsetAsync dispatch (counts/embsum/loss/nsum zeroed
// here via float4 grid-stride) — each dispatch boundary costs ~10us of launch/
// gap time. enmax is GONE: vq_main computes max(enorm) itself during its en_s
// load (bit-identical max, no cross-dispatch atomic needed).
__global__ void vq_eprep(const float* __restrict__ E, float* __restrict__ enorm,
                         u16* __restrict__ E16, float* __restrict__ zero0) {
  int gid = blockIdx.x * 256 + threadIdx.x;   // 32 blocks -> 0..8191
  if (gid < K_) {
    float v = pw256_sq(E + gid * D_, 1);
    enorm[gid] = v;
  }
  unsigned* E16w = (unsigned*)E16;
  for (int wd = gid; wd < (K_ * D_ / 2); wd += 8192) {
    float2 x = *(const float2*)(E + 2 * wd);
    E16w[wd] = f16x2pack(512.0f * x.x, 512.0f * x.y);
  }
  // zero counts(4KB)+embsum(1MB)+loss+nsum: 65792 float4 + 2 floats
  float4 z4 = {0.f, 0.f, 0.f, 0.f};
  float4* zp = (float4*)zero0;
  for (int i = gid; i < 65792; i += 8192) zp[i] = z4;
  if (gid == 0) { zero0[263168] = 0.f; zero0[263169] = 0.f; }  // loss, nsum
}

// VALU-speed 16-lane min via DPP (quad_perm ^1, ^2, row_half_mirror, row_mirror)
template <int CTRL>
__device__ __forceinline__ float dppmin(float v) {
  int p = __builtin_amdgcn_update_dpp(0, __float_as_int(v), CTRL, 0xF, 0xF, true);
  return fminf(v, __int_as_float(p));
}

// Exact reference-numerics distance (np-order sequential fp32 FMA over d, then
// fl(fl(zn-2a)+en)); z row from LDS (contiguous f32), E row from global.
// Key=(score_bits<<32)|code -> LDS u64 atomicMin (block-final best; lowest
// code wins ties = np argmin). forceinline: only 2 call sites, both AFTER the
// MFMA loop (round-3 lesson: no calls with live acc/ef).
__device__ __forceinline__ void exact_update(
    const float* zrow, const float* __restrict__ E, int t, int c,
    const float* zn_s, const float* en_s, unsigned long long* best_s) {
  const float* ep = E + c * D_;
  float a = 0.f;
  for (int d0 = 0; d0 < 256; d0 += 8) {
    f32x4 z0 = *(const f32x4*)(zrow + d0);
    f32x4 z1 = *(const f32x4*)(zrow + d0 + 4);
    float4 e0 = *(const float4*)(ep + d0);
    float4 e1 = *(const float4*)(ep + d0 + 4);
    a = __fmaf_rn(z0[0], e0.x, a); a = __fmaf_rn(z0[1], e0.y, a);
    a = __fmaf_rn(z0[2], e0.z, a); a = __fmaf_rn(z0[3], e0.w, a);
    a = __fmaf_rn(z1[0], e1.x, a); a = __fmaf_rn(z1[1], e1.y, a);
    a = __fmaf_rn(z1[2], e1.z, a); a = __fmaf_rn(z1[3], e1.w, a);
  }
  float s = __fadd_rn(__fsub_rn(zn_s[t], __fmul_rn(2.0f, a)), en_s[c]);
  unsigned long long key = ((unsigned long long)__float_as_uint(s) << 32) | (unsigned)c;
  atomicMin(&best_s[t], key);
}

#define TCAP 96   // per-wave trigger list (expected ~24 used w/ fp16 margin)
#define ZP  260   // zs row pad: 260*4B = 1040 ≡ 0 mod 16 (b128-aligned rows)

// ---------------- FUSED dist + scatter (round-9 kernel; loop byte-frozen) ----------------
// 1024 blocks x 256 thr, ~39.6 KB LDS -> 4 blocks/CU. Block = 32 tokens x ALL
// 1024 codes => best is block-final (no cross-block merge) => scatter fuses in.
// Measured clean (r9/r12): 127us, VGPR=64, no spill. Rounds 10/11 rewrites of
// this body both collapsed to VGPR=40 + scratch spill -> loop NOT restructured.
// ROUND-13 delta (preamble only): en_max computed locally during the en_s load
// (per-thread fmax + wave shfl + wred[]) instead of reading a global enmax —
// same max value bit-identical, no liveness into the MFMA loop.
// Phase A: MFMA fp16 approx scores (z cvt'd f32->f16 on the fly from the LDS
// f32 tile), per-token running min, margin-gated trigger list, exact fp32
// re-verify into LDS best_s. Margin M = 2^-8*sqrt(zn*en_max)+5e-4 (2x the
// rigorous two-sided fp16 bound) -> reference argmin always triggers.
// Phase B: scatter body on the same LDS tile (loss, z_q_st in-place,
// embsum atomics, counts, idx).
__global__ __launch_bounds__(256, 4) void vq_main(
    const float* __restrict__ z, const float* __restrict__ E,
    const u16* __restrict__ E16, const float* __restrict__ enorm,
    float* __restrict__ embsum, float* __restrict__ loss_sum,
    float* __restrict__ counts, float* __restrict__ out_zq,
    float* __restrict__ out_idx) {
  __shared__ __align__(16) float zs[32 * ZP];            // 33280 B, [tok][d]
  __shared__ float en_s[K_];                              // 4 KiB
  __shared__ float zn_s[32];
  __shared__ float mg_s[32];
  __shared__ unsigned rmin_s[32];                         // bits of (min ph)+4.0
  __shared__ unsigned long long best_s[32];
  __shared__ unsigned tcount[4];
  __shared__ unsigned tlist[4][TCAP];                     // 1.5 KiB
  __shared__ float wred[4];

  const int tid = threadIdx.x;
  const int tile = blockIdx.x;               // 0..1023
  const int bimg = tile >> 5;
  const int hw0 = (tile & 31) << 5;          // 32 tokens
  const float* zb = z + bimg * (D_ * HW_) + hw0;
  const int n0 = bimg * HW_ + hw0;

  // stage z f32 -> zs[t][d] (coalesced float4 global reads, scalar LDS writes)
#pragma unroll
  for (int r = 0; r < 8; ++r) {
    int ii = r * 256 + tid;
    int d = ii >> 3, t4 = (ii & 7) * 4;
    float4 v = *(const float4*)(zb + d * HW_ + t4);
    zs[(t4 + 0) * ZP + d] = v.x; zs[(t4 + 1) * ZP + d] = v.y;
    zs[(t4 + 2) * ZP + d] = v.z; zs[(t4 + 3) * ZP + d] = v.w;
  }
  // en_s load + local en_max (replaces the old global enmax; bit-identical max)
  {
    float emx = 0.f;
    for (int i = tid; i < K_; i += 256) {
      float v = enorm[i];
      en_s[i] = v;
      emx = fmaxf(emx, v);
    }
#pragma unroll
    for (int o = 32; o > 0; o >>= 1) emx = fmaxf(emx, __shfl_down(emx, o, 64));
    if ((tid & 63) == 0) wred[tid >> 6] = emx;
  }
  if (tid < 4) tcount[tid] = 0;
  __syncthreads();
  if (tid < 32) {
    float zn = pw256_sq(&zs[tid * ZP], 1);   // np order, bit-identical values
    zn_s[tid] = zn;
    float em = fmaxf(fmaxf(wred[0], wred[1]), fmaxf(wred[2], wred[3]));
    mg_s[tid] = 0.00390625f * sqrtf(zn * em) + 5e-4f;  // fp16 margin (proven safe)
    rmin_s[tid] = 0xFFFFFFFFu;
    best_s[tid] = ~0ull;
  }
  __syncthreads();

  const int lane = tid & 63;
  const int w = tid >> 6;
  const int l15 = lane & 15, g = lane >> 4;
  const int cw = w * 256;                    // wave's code base
  const u16* Eb = E16 + (unsigned)(cw + l15) * D_ + g * 8;

  f16x8 efA[2], efB[2];
#pragma unroll
  for (int n = 0; n < 2; ++n)
    efA[n] = *(const f16x8*)(Eb + n * 16 * D_);          // prime: s=0 (ch0,kk0)

  f32x4 acc[2][2];

// one MFMA step: ef ping-pong (dist-1; best-measured), z fragment read as f32
// from zs + cvt to fp16 (same rne values as the old pre-converted tile).
// No branches, no calls in the loop.
#define MSTEP(S, EFU, EFF, SN)                                                   \
  {                                                                              \
    const int kk_ = (S) & 7;                                                     \
    {                                                                            \
      const int cn_ = (SN) >> 3, kn_ = (SN) & 7;                                 \
      _Pragma("unroll")                                                          \
      for (int n = 0; n < 2; ++n)                                                \
        EFF[n] = *(const f16x8*)(Eb + (cn_ * 32 + n * 16) * D_ + kn_ * 32);      \
    }                                                                            \
    f16x8 zf_[2];                                                                \
    _Pragma("unroll")                                                            \
    for (int m = 0; m < 2; ++m) {                                                \
      const float* zr = zs + (m * 16 + l15) * ZP + kk_ * 32 + g * 8;             \
      f32x4 lo = *(const f32x4*)zr;                                              \
      f32x4 hi = *(const f32x4*)(zr + 4);                                        \
      f16x8 zc;                                                                  \
      _Pragma("unroll")                                                          \
      for (int j = 0; j < 4; ++j) {                                              \
        zc[j] = (_Float16)lo[j]; zc[4 + j] = (_Float16)hi[j];                    \
      }                                                                          \
      zf_[m] = zc;                                                               \
    }                                                                            \
    _Pragma("unroll")                                                            \
    for (int m = 0; m < 2; ++m)                                                  \
      _Pragma("unroll")                                                          \
      for (int n = 0; n < 2; ++n)                                                \
        acc[m][n] = __builtin_amdgcn_mfma_f32_16x16x32_f16(zf_[m], EFU[n],       \
                                                           acc[m][n], 0, 0, 0);  \
  }

  for (int s2 = 0; s2 < 64; s2 += 2) {      // 8 chunks x 8 kk
    if ((s2 & 7) == 0) {
      f32x4 z4 = {0.f, 0.f, 0.f, 0.f};
#pragma unroll
      for (int m = 0; m < 2; ++m)
#pragma unroll
        for (int n = 0; n < 2; ++n) acc[m][n] = z4;
    }
    MSTEP(s2, efA, efB, s2 + 1)
    MSTEP(s2 + 1, efB, efA, (s2 + 2) & 63)   // tail wrap value never consumed
    if ((s2 & 7) == 6) {                     // chunk end
      const int cb = cw + (s2 >> 3) * 32;
      // ph = en - 2*(A/512) = fma(-1/256, A, en); D: col=l15(code), row=g*4+r(tok)
      float enc[2];
#pragma unroll
      for (int n = 0; n < 2; ++n) enc[n] = en_s[cb + n * 16 + l15];
#pragma unroll
      for (int m = 0; m < 2; ++m)
#pragma unroll
        for (int n = 0; n < 2; ++n)
#pragma unroll
          for (int r = 0; r < 4; ++r)
            acc[m][n][r] = __builtin_fmaf(-0.00390625f, acc[m][n][r], enc[n]);
#pragma unroll
      for (int m = 0; m < 2; ++m)
#pragma unroll
        for (int r = 0; r < 4; ++r) {
          float v = fminf(acc[m][0][r], acc[m][1][r]);
          v = dppmin<0xB1>(v);     // ^1
          v = dppmin<0x4E>(v);     // ^2
          v = dppmin<0x141>(v);    // row_half_mirror
          v = dppmin<0x140>(v);    // row_mirror
          if (l15 == 0) atomicMin(&rmin_s[m * 16 + g * 4 + r], __float_as_uint(v + 4.0f));
        }
#pragma unroll
      for (int m = 0; m < 2; ++m)
#pragma unroll
        for (int r = 0; r < 4; ++r) {
          int t = m * 16 + g * 4 + r;
          float thr = (__uint_as_float(rmin_s[t]) - 4.0f) + mg_s[t];
#pragma unroll
          for (int n = 0; n < 2; ++n) {
            if (acc[m][n][r] <= thr) {
              unsigned pos = atomicAdd(&tcount[w], 1u);
              if (pos < TCAP)
                tlist[w][pos] = ((unsigned)t << 16) | (unsigned)(cb + n * 16 + l15);
            }
          }
        }
    }
  }
#undef MSTEP

  // drain own wave's triggers: exact recompute (LDS z row + global E) -> best_s
  {
    unsigned cnt = tcount[w];
    if (cnt <= TCAP) {
      for (unsigned basei = 0; basei < cnt; basei += 64) {
        unsigned i = basei + (unsigned)lane;
        if (i < cnt) {
          unsigned e = tlist[w][i];
          int t = (int)(e >> 16), c = (int)(e & 1023u);
          exact_update(&zs[t * ZP], E, t, c, zn_s, en_s, best_s);
        }
      }
    } else {
      // overflow (astronomically rare): exact-verify wave's whole 32x256 tile
      for (unsigned i = (unsigned)lane; i < 32u * 256u; i += 64) {
        int t = (int)(i >> 8), c = cw + (int)(i & 255u);
        exact_update(&zs[t * ZP], E, t, c, zn_s, en_s, best_s);
      }
    }
  }
  __syncthreads();   // best_s final; zs reads done -> phase B may overwrite

  // ---------------- phase B: scatter body on the same LDS tile ----------------
  if (tid < 32) {
    int k = (int)(best_s[tid] & 1023ull);
    out_idx[n0 + tid] = (float)k;
    atomicAdd(&counts[k], 1.0f);
  }
  float lsum = 0.f;
  for (int tt = 0; tt < 8; ++tt) {
    int t = w * 8 + tt;
    int k = (int)(best_s[t] & 1023ull);    // wave-uniform
    const float* Er = E + k * D_;
    float* es = embsum + k * D_;
#pragma unroll
    for (int i = 0; i < 4; ++i) {
      int d = i * 64 + lane;
      float e = Er[d];
      float zv = zs[t * ZP + d];           // unique (t,d) owner -> safe in-place
      float df = __fsub_rn(zv, e);
      lsum += df * df;
      zs[t * ZP + d] = __fadd_rn(zv, __fsub_rn(e, zv));  // ref: z + (z_q - z)
      atomicAdd(es + d, zv);
    }
  }
#pragma unroll
  for (int o = 32; o > 0; o >>= 1) lsum += __shfl_down(lsum, o, 64);
  if (lane == 0) wred[w] = lsum;
  __syncthreads();
  if (tid == 0) atomicAdd(loss_sum, wred[0] + wred[1] + wred[2] + wred[3]);

  float* ob = out_zq + bimg * (D_ * HW_) + hw0;
#pragma unroll 4
  for (int r = 0; r < 32; ++r) {
    int d = r * 8 + (tid >> 5);
    int t = tid & 31;
    ob[d * HW_ + t] = zs[t * ZP + d];      // coalesced 128B-chunk f32 stores
  }
}

// ---------------- fused EMA finalize: newcs + nsum + loss + newemb ----------------
// 1024 blocks x 256 thr. Every block redundantly computes the full 1024-element
// nsum (identical code + data + order in each block -> bit-identical n across
// blocks; ~8KB of L2-broadcast reads). Replaces the old newcs->newemb
// 2-dispatch handoff (each dispatch boundary ~10us).
__global__ void vq_newfin(const float* __restrict__ cs_in, const float* __restrict__ counts,
                          const float* __restrict__ es_in, const float* __restrict__ embsum,
                          const float* __restrict__ loss_sum,
                          float* __restrict__ out_loss, float* __restrict__ out_ncs,
                          float* __restrict__ out_emb, float* __restrict__ out_nes) {
  __shared__ float nred[4];
  const int k = blockIdx.x, d = threadIdx.x;
  float s = 0.f;
  float myv[4];
#pragma unroll
  for (int i = 0; i < 4; ++i) {
    int idx = i * 256 + d;
    float v = __fadd_rn(__fmul_rn(0.99f, cs_in[idx]), __fmul_rn(0.01f, counts[idx]));
    myv[i] = v;
    s += v;
  }
#pragma unroll
  for (int o = 32; o > 0; o >>= 1) s += __shfl_down(s, o, 64);
  if ((d & 63) == 0) nred[d >> 6] = s;
  __syncthreads();
  const float n = (nred[0] + nred[1]) + (nred[2] + nred[3]);
  if (d == (k & 255)) out_ncs[k] = myv[k >> 8];      // block k owns element k
  if (k == 0 && d == 0) out_loss[0] = loss_sum[0] * (1.0f / 8388608.0f);
  float vk = __fadd_rn(__fmul_rn(0.99f, cs_in[k]), __fmul_rn(0.01f, counts[k]));
  float cs = (vk + 1e-5f) / (n + 1024.0f * 1e-5f) * n;   // ref formula order
  float es = __fadd_rn(__fmul_rn(0.99f, es_in[k * D_ + d]),
                       __fmul_rn(0.01f, embsum[k * D_ + d]));
  out_nes[k * D_ + d] = es;
  out_emb[k * D_ + d] = es / cs;
}

extern "C" void kernel_launch(void* const* d_in, const int* in_sizes, int n_in,
                              void* d_out, int out_size, void* d_ws, size_t ws_size,
                              hipStream_t stream) {
  (void)in_sizes; (void)n_in; (void)out_size; (void)ws_size;
  const float* z       = (const float*)d_in[0];
  const float* E       = (const float*)d_in[1];
  const float* ema_cs  = (const float*)d_in[2];
  const float* ema_es  = (const float*)d_in[3];
  float* out = (float*)d_out;
  char* ws = (char*)d_ws;
  float* counts = (float*)(ws + WS_COUNTS);
  float* embsum = (float*)(ws + WS_EMBSUM);
  float* loss_s = (float*)(ws + WS_LOSS);
  float* enorm  = (float*)(ws + WS_ENORM);
  u16*   e16    = (u16*)(ws + WS_E16);

  // 3 dispatches (was 5): memset folded into eprep; newcs folded into newfin.
  vq_eprep<<<dim3(32), dim3(256), 0, stream>>>(E, enorm, e16, counts);
  vq_main<<<dim3(1024), dim3(256), 0, stream>>>(z, E, e16, enorm,
                                                embsum, loss_s, counts,
                                                out + O_ZQ, out + O_IDX);
  vq_newfin<<<dim3(K_), dim3(256), 0, stream>>>(ema_cs, counts, ema_es, embsum,
                                                loss_s, out + O_LOSS, out + O_NCS,
                                                out + O_EMB, out + O_NES);
}